// Round 3
// baseline (209.715 us; speedup 1.0000x reference)
//
#include <hip/hip_runtime.h>
#include <math.h>

// B=8, T=4096, H=8, D=64, fp32.
// Single deterministic 3-kernel pipeline, NCv=512 chunks (L=8):
//   k_agg  : 4096 blocks, reads inputs once, writes 8 MB aggregates Z
//   k_scan : 512 blocks, scans aggregates IN-PLACE (P overwrites Z)
//   k_out  : 4096 blocks, re-reads (L3-hot) inputs + carry, writes out once
#define BB 8
#define TT 4096
#define HH 8
#define NCV 512
#define LCV (TT / NCV)        // 8 steps per chunk
#define GRID (BB * NCV)       // 4096 blocks

typedef float f32x4 __attribute__((ext_vector_type(4)));

__device__ __forceinline__ float sigmoidf_(float x) {
    return 1.0f / (1.0f + expf(-x));
}

// ---------------------------------------------------------------------------
// K1: per-(b,chunk) block of 128 threads (thread = (h,d4), float4 over D).
// Full-occupancy streaming: 4096 blocks x 2 waves = 8192 waves (100%),
// __launch_bounds__(128,8) caps VGPR at 64 -> 16 blocks/CU.
// All 16 loads of the chunk issued as explicit batches.
// ---------------------------------------------------------------------------
__global__ __launch_bounds__(128, 8)
void k_agg(const float4* __restrict__ vals, const float4* __restrict__ aux,
           const float* __restrict__ w, float4* __restrict__ Z) {
    const int blk = blockIdx.x;
    const int b = blk >> 9;            // blk / NCV
    const int c = blk & (NCV - 1);
    const int tid = threadIdx.x;
    const int h = tid >> 4;

    const float alpha = sigmoidf_(w[h]);
    const float onem  = 1.0f - alpha;
    const float fa    = (onem / fmaxf(onem, 1e-6f)) * alpha;

    // float4 index: ((b*T+t)*H + h)*D/4 + d4 = (b*T+t)*128 + tid
    const int base = (b * TT + c * LCV) * 128 + tid;

    float4 v[LCV], a[LCV];
#pragma unroll
    for (int i = 0; i < LCV; ++i) v[i] = vals[base + i * 128];
#pragma unroll
    for (int i = 0; i < LCV; ++i) a[i] = aux[base + i * 128];

    float4 yy = make_float4(0.f, 0.f, 0.f, 0.f);
#pragma unroll
    for (int i = 0; i < LCV; ++i) {
        yy.x = alpha * yy.x + onem * v[i].x + fa * a[i].x;
        yy.y = alpha * yy.y + onem * v[i].y + fa * a[i].y;
        yy.z = alpha * yy.z + onem * v[i].z + fa * a[i].z;
        yy.w = alpha * yy.w + onem * v[i].w + fa * a[i].w;
    }
    Z[(b * NCV + c) * 128 + tid] = yy;
}

// ---------------------------------------------------------------------------
// K2: Kogge-Stone scan over the NCV chunk aggregates, IN-PLACE (P == Z).
// Block = (b, h, d8): 8*8*8 = 512 blocks, NCV threads (thread = chunk c).
// Each thread owns one chunk row of 8 floats. All global reads happen
// before the first global write (separated by __syncthreads rounds), and
// blocks write exactly the slice they read -> in-place is safe.
// Combine: S[c] += aL^off * S[c-off].  P[c] = aL^c * v0 + S_inc[c-1].
// LDS row stride 9 floats -> conflict-free.
// ---------------------------------------------------------------------------
__global__ __launch_bounds__(NCV)
void k_scan(float4* __restrict__ ZP, const float* __restrict__ v0,
            const float* __restrict__ w) {
    __shared__ float lds[NCV][9];

    const int blk = blockIdx.x;        // b*64 + h*8 + d8
    const int b  = blk >> 6;
    const int h  = (blk >> 3) & 7;
    const int d8 = blk & 7;
    const int r4 = h * 16 + d8 * 2;    // float4 offset within 128-f4 row
    const int tid = threadIdx.x;

    const float alpha = sigmoidf_(w[h]);
    const float aL = powf(alpha, (float)LCV);

    // Each thread loads its own chunk's 8-float slice (2 float4).
    {
        float4 z0 = ZP[(b * NCV + tid) * 128 + r4];
        float4 z1 = ZP[(b * NCV + tid) * 128 + r4 + 1];
        lds[tid][0] = z0.x; lds[tid][1] = z0.y; lds[tid][2] = z0.z; lds[tid][3] = z0.w;
        lds[tid][4] = z1.x; lds[tid][5] = z1.y; lds[tid][6] = z1.z; lds[tid][7] = z1.w;
    }
    __syncthreads();

    const int c = tid;    // thread c owns chunk c's 8-float row
    float s[8];
#pragma unroll
    for (int k = 0; k < 8; ++k) s[k] = lds[c][k];

    float m = aL;
    for (int off = 1; off < NCV; off <<= 1) {
        float tmp[8];
        const bool act = (c >= off);
        if (act) {
#pragma unroll
            for (int k = 0; k < 8; ++k) tmp[k] = lds[c - off][k];
        }
        __syncthreads();
        if (act) {
#pragma unroll
            for (int k = 0; k < 8; ++k) { s[k] += m * tmp[k]; lds[c][k] = s[k]; }
        }
        m *= m;
        __syncthreads();
    }

    // Carry into chunk c: P[c] = alpha^(L*c) * v0 + S_inc[c-1]; P[0] = v0.
    const float pc = powf(alpha, (float)(LCV * c));
    const float4* v04 = (const float4*)v0;
#pragma unroll
    for (int k = 0; k < 2; ++k) {
        float4 vv = v04[r4 + k];
        float4 pr;
        if (c == 0) {
            pr = vv;
        } else {
            pr.x = pc * vv.x + lds[c - 1][k * 4 + 0];
            pr.y = pc * vv.y + lds[c - 1][k * 4 + 1];
            pr.z = pc * vv.z + lds[c - 1][k * 4 + 2];
            pr.w = pc * vv.w + lds[c - 1][k * 4 + 3];
        }
        ZP[(b * NCV + c) * 128 + r4 + k] = pr;   // in-place: P over Z
    }
}

// ---------------------------------------------------------------------------
// K3: recompute local scan from (L3-hot) inputs, fold in carry, write out
// once with non-temporal stores. Full occupancy like k_agg.
//   out[t=c*L+i] = y_local[i] + alpha^(i+1) * P[c]
// ---------------------------------------------------------------------------
__global__ __launch_bounds__(128, 8)
void k_out(const float4* __restrict__ vals, const float4* __restrict__ aux,
           const float* __restrict__ w, const float4* __restrict__ P,
           float4* __restrict__ out) {
    const int blk = blockIdx.x;
    const int b = blk >> 9;
    const int c = blk & (NCV - 1);
    const int tid = threadIdx.x;
    const int h = tid >> 4;

    const float alpha = sigmoidf_(w[h]);
    const float onem  = 1.0f - alpha;
    const float fa    = (onem / fmaxf(onem, 1e-6f)) * alpha;

    const float4 p = P[(b * NCV + c) * 128 + tid];
    const int base = (b * TT + c * LCV) * 128 + tid;

    float4 v[LCV], a[LCV];
#pragma unroll
    for (int i = 0; i < LCV; ++i) v[i] = vals[base + i * 128];
#pragma unroll
    for (int i = 0; i < LCV; ++i) a[i] = aux[base + i * 128];

    float4 yy = make_float4(0.f, 0.f, 0.f, 0.f);
    float coef = alpha;
#pragma unroll
    for (int i = 0; i < LCV; ++i) {
        yy.x = alpha * yy.x + onem * v[i].x + fa * a[i].x;
        yy.y = alpha * yy.y + onem * v[i].y + fa * a[i].y;
        yy.z = alpha * yy.z + onem * v[i].z + fa * a[i].z;
        yy.w = alpha * yy.w + onem * v[i].w + fa * a[i].w;
        float4 o;
        o.x = yy.x + coef * p.x;
        o.y = yy.y + coef * p.y;
        o.z = yy.z + coef * p.z;
        o.w = yy.w + coef * p.w;
        __builtin_nontemporal_store(*(const f32x4*)&o, (f32x4*)&out[base + i * 128]);
        coef *= alpha;
    }
}

// ---------------------------------------------------------------------------
extern "C" void kernel_launch(void* const* d_in, const int* in_sizes, int n_in,
                              void* d_out, int out_size, void* d_ws, size_t ws_size,
                              hipStream_t stream) {
    const float4* vals = (const float4*)d_in[0];   // values  [B,T,H,D]
    const float4* aux  = (const float4*)d_in[1];   // aux     [B,T,H,D]
    const float*  v0   = (const float*)d_in[2];    // v0      [H,D] = 512
    const float*  w    = (const float*)d_in[3];    // weight  [H] = 8
    float4* out = (float4*)d_out;

    // Workspace: single Z/P buffer, B*NCV*128 float4 = 8.39 MB (in-place scan).
    float4* ZP = (float4*)d_ws;

    k_agg <<<GRID, 128, 0, stream>>>(vals, aux, w, ZP);
    k_scan<<<BB * HH * 8, NCV, 0, stream>>>(ZP, v0, w);
    k_out <<<GRID, 128, 0, stream>>>(vals, aux, w, ZP, out);
}

// Round 5
// 208.451 us; speedup vs baseline: 1.0061x; 1.0061x over previous
//
#include <hip/hip_runtime.h>
#include <math.h>

// B=8, T=4096, H=8, D=64, fp32.
// 3-kernel pipeline, NCV=512 chunks (L=8):
//   k_agg  : forced-deep streaming read, writes 8 MB aggregates Z
//   k_scan : scans aggregates IN-PLACE (P overwrites Z)
//   k_out  : forced-deep nt re-read of inputs + carry, single nt write of out
#define BB 8
#define TT 4096
#define HH 8
#define NCV 512
#define LCV (TT / NCV)          // 8 steps per chunk
#define GRID2 (BB * NCV / 2)    // 2048 blocks of 256 threads (2 chunks each)

typedef float f32x4 __attribute__((ext_vector_type(4)));

__device__ __forceinline__ float sigmoidf_(float x) {
    return 1.0f / (1.0f + expf(-x));
}

// ---------------------------------------------------------------------------
// K1: block = 256 threads = 2 chunks; thread = (chunk-of-pair, h, d4).
// All 16 dwordx4 loads of the chunk are issued BEFORE the first FMA —
// enforced by sched_barrier(0); __launch_bounds__(256,4) allows 128 VGPRs
// so the batch (64 VGPRs) is register-resident. 16 waves/CU.
// ---------------------------------------------------------------------------
__global__ __launch_bounds__(256, 4)
void k_agg(const f32x4* __restrict__ vals, const f32x4* __restrict__ aux,
           const float* __restrict__ w, f32x4* __restrict__ Z) {
    const int blk = blockIdx.x;
    const int b   = blk >> 8;             // 256 chunk-pairs per batch
    const int cp  = blk & 255;
    const int tid = threadIdx.x;
    const int lane = tid & 127;           // (h, d4)
    const int c   = cp * 2 + (tid >> 7);  // chunk of this half-block
    const int h   = lane >> 4;

    const float alpha = sigmoidf_(w[h]);
    const float onem  = 1.0f - alpha;
    const float fa    = (onem / fmaxf(onem, 1e-6f)) * alpha;

    // f32x4 index: (b*T + t)*128 + lane
    const int base = (b * TT + c * LCV) * 128 + lane;

    f32x4 v[LCV], a[LCV];
#pragma unroll
    for (int i = 0; i < LCV; ++i) v[i] = vals[base + i * 128];
#pragma unroll
    for (int i = 0; i < LCV; ++i) a[i] = aux[base + i * 128];
    __builtin_amdgcn_sched_barrier(0);    // all 16 loads issued before compute

    f32x4 y; y.x = 0.f; y.y = 0.f; y.z = 0.f; y.w = 0.f;
#pragma unroll
    for (int i = 0; i < LCV; ++i) {
        y.x = alpha * y.x + onem * v[i].x + fa * a[i].x;
        y.y = alpha * y.y + onem * v[i].y + fa * a[i].y;
        y.z = alpha * y.z + onem * v[i].z + fa * a[i].z;
        y.w = alpha * y.w + onem * v[i].w + fa * a[i].w;
    }
    Z[(b * NCV + c) * 128 + lane] = y;
}

// ---------------------------------------------------------------------------
// K2: Kogge-Stone scan over the NCV chunk aggregates, IN-PLACE (P == Z).
// Block = (b, h, d8): 512 blocks, NCV threads (thread = chunk c).
// All global reads complete (sync'd) before the first global write; each
// block writes exactly the slice it read -> in-place safe.
// P[c] = alpha^(L*c) * v0 + S_inc[c-1]; P[0] = v0. Row stride 9: no conflicts.
// ---------------------------------------------------------------------------
__global__ __launch_bounds__(NCV)
void k_scan(float4* __restrict__ ZP, const float* __restrict__ v0,
            const float* __restrict__ w) {
    __shared__ float lds[NCV][9];

    const int blk = blockIdx.x;        // b*64 + h*8 + d8
    const int b  = blk >> 6;
    const int h  = (blk >> 3) & 7;
    const int d8 = blk & 7;
    const int r4 = h * 16 + d8 * 2;
    const int tid = threadIdx.x;

    const float alpha = sigmoidf_(w[h]);
    const float aL = powf(alpha, (float)LCV);

    {
        float4 z0 = ZP[(b * NCV + tid) * 128 + r4];
        float4 z1 = ZP[(b * NCV + tid) * 128 + r4 + 1];
        lds[tid][0] = z0.x; lds[tid][1] = z0.y; lds[tid][2] = z0.z; lds[tid][3] = z0.w;
        lds[tid][4] = z1.x; lds[tid][5] = z1.y; lds[tid][6] = z1.z; lds[tid][7] = z1.w;
    }
    __syncthreads();

    const int c = tid;
    float s[8];
#pragma unroll
    for (int k = 0; k < 8; ++k) s[k] = lds[c][k];

    float m = aL;
    for (int off = 1; off < NCV; off <<= 1) {
        float tmp[8];
        const bool act = (c >= off);
        if (act) {
#pragma unroll
            for (int k = 0; k < 8; ++k) tmp[k] = lds[c - off][k];
        }
        __syncthreads();
        if (act) {
#pragma unroll
            for (int k = 0; k < 8; ++k) { s[k] += m * tmp[k]; lds[c][k] = s[k]; }
        }
        m *= m;
        __syncthreads();
    }

    const float pc = powf(alpha, (float)(LCV * c));
    const float4* v04 = (const float4*)v0;
#pragma unroll
    for (int k = 0; k < 2; ++k) {
        float4 vv = v04[r4 + k];
        float4 pr;
        if (c == 0) {
            pr = vv;
        } else {
            pr.x = pc * vv.x + lds[c - 1][k * 4 + 0];
            pr.y = pc * vv.y + lds[c - 1][k * 4 + 1];
            pr.z = pc * vv.z + lds[c - 1][k * 4 + 2];
            pr.w = pc * vv.w + lds[c - 1][k * 4 + 3];
        }
        ZP[(b * NCV + c) * 128 + r4 + k] = pr;   // in-place: P over Z
    }
}

// ---------------------------------------------------------------------------
// K3: same forced-deep structure; inputs re-read with NON-TEMPORAL loads
// (last use — keep L3 for the write stream), carry folded in, out written
// once with nt stores.   out[t=c*L+i] = y_local[i] + alpha^(i+1) * P[c]
// ---------------------------------------------------------------------------
__global__ __launch_bounds__(256, 4)
void k_out(const f32x4* __restrict__ vals, const f32x4* __restrict__ aux,
           const float* __restrict__ w, const f32x4* __restrict__ P,
           f32x4* __restrict__ out) {
    const int blk = blockIdx.x;
    const int b   = blk >> 8;
    const int cp  = blk & 255;
    const int tid = threadIdx.x;
    const int lane = tid & 127;
    const int c   = cp * 2 + (tid >> 7);
    const int h   = lane >> 4;

    const float alpha = sigmoidf_(w[h]);
    const float onem  = 1.0f - alpha;
    const float fa    = (onem / fmaxf(onem, 1e-6f)) * alpha;

    const f32x4 p = P[(b * NCV + c) * 128 + lane];
    const int base = (b * TT + c * LCV) * 128 + lane;

    f32x4 v[LCV], a[LCV];
#pragma unroll
    for (int i = 0; i < LCV; ++i) v[i] = __builtin_nontemporal_load(&vals[base + i * 128]);
#pragma unroll
    for (int i = 0; i < LCV; ++i) a[i] = __builtin_nontemporal_load(&aux[base + i * 128]);
    __builtin_amdgcn_sched_barrier(0);    // all 16 loads issued before compute

    f32x4 y; y.x = 0.f; y.y = 0.f; y.z = 0.f; y.w = 0.f;
    float coef = alpha;
#pragma unroll
    for (int i = 0; i < LCV; ++i) {
        y.x = alpha * y.x + onem * v[i].x + fa * a[i].x;
        y.y = alpha * y.y + onem * v[i].y + fa * a[i].y;
        y.z = alpha * y.z + onem * v[i].z + fa * a[i].z;
        y.w = alpha * y.w + onem * v[i].w + fa * a[i].w;
        f32x4 o;
        o.x = y.x + coef * p.x;
        o.y = y.y + coef * p.y;
        o.z = y.z + coef * p.z;
        o.w = y.w + coef * p.w;
        __builtin_nontemporal_store(o, &out[base + i * 128]);
        coef *= alpha;
    }
}

// ---------------------------------------------------------------------------
extern "C" void kernel_launch(void* const* d_in, const int* in_sizes, int n_in,
                              void* d_out, int out_size, void* d_ws, size_t ws_size,
                              hipStream_t stream) {
    const f32x4* vals = (const f32x4*)d_in[0];   // values  [B,T,H,D]
    const f32x4* aux  = (const f32x4*)d_in[1];   // aux     [B,T,H,D]
    const float* v0   = (const float*)d_in[2];   // v0      [H,D] = 512
    const float* w    = (const float*)d_in[3];   // weight  [H] = 8
    f32x4* out = (f32x4*)d_out;

    // Workspace: single Z/P buffer, B*NCV*128 f32x4 = 8.39 MB (in-place scan).
    f32x4* ZP = (f32x4*)d_ws;

    k_agg <<<GRID2, 256, 0, stream>>>(vals, aux, w, ZP);
    k_scan<<<BB * HH * 8, NCV, 0, stream>>>((float4*)ZP, v0, w);
    k_out <<<GRID2, 256, 0, stream>>>(vals, aux, w, ZP, out);
}

// Round 6
// 204.466 us; speedup vs baseline: 1.0257x; 1.0195x over previous
//
#include <hip/hip_runtime.h>
#include <math.h>

// B=8, T=4096, H=8, D=64, fp32.
// R0-structure revival (minimal READ bytes), tuned:
//   k_partial : reads inputs ONCE (128 MB), writes partial-out (64) + Z (8)
//   k_scan    : scans chunk aggregates IN-PLACE (P overwrites Z)
//   k_final   : RMW fix-up: reads out (L3-hot) + P, writes out once (nt)
// Total: 208 MB reads + 136 MB writes. vs R5: 272 reads + 80 writes.
#define BB 8
#define TT 4096
#define HH 8
#define NCV 512
#define LCV (TT / NCV)        // 8 steps per chunk
#define GRID (BB * NCV)       // 4096 blocks

typedef float f32x4 __attribute__((ext_vector_type(4)));

__device__ __forceinline__ float sigmoidf_(float x) {
    return 1.0f / (1.0f + expf(-x));
}

// ---------------------------------------------------------------------------
// K1: per-(b,chunk) block of 128 threads (thread = (h,d4), float4 over D).
// Zero-init local scan; stream partial prefixes to out (plain stores keep
// them L3-resident for k_final's re-read); write chunk aggregate Z.
// ---------------------------------------------------------------------------
__global__ __launch_bounds__(128)
void k_partial(const f32x4* __restrict__ vals, const f32x4* __restrict__ aux,
               const float* __restrict__ w, f32x4* __restrict__ out,
               f32x4* __restrict__ Z) {
    const int blk = blockIdx.x;
    const int b = blk >> 9;            // blk / NCV
    const int c = blk & (NCV - 1);
    const int tid = threadIdx.x;
    const int h = tid >> 4;

    const float alpha = sigmoidf_(w[h]);
    const float onem  = 1.0f - alpha;
    const float fa    = (onem / fmaxf(onem, 1e-6f)) * alpha;

    // f32x4 index: ((b*T+t)*H + h)*D/4 + d4 = (b*T+t)*128 + tid
    const int base = (b * TT + c * LCV) * 128 + tid;

    f32x4 y; y.x = 0.f; y.y = 0.f; y.z = 0.f; y.w = 0.f;
#pragma unroll
    for (int i = 0; i < LCV; ++i) {
        f32x4 v = vals[base + i * 128];
        f32x4 a = aux[base + i * 128];
        y.x = alpha * y.x + onem * v.x + fa * a.x;
        y.y = alpha * y.y + onem * v.y + fa * a.y;
        y.z = alpha * y.z + onem * v.z + fa * a.z;
        y.w = alpha * y.w + onem * v.w + fa * a.w;
        out[base + i * 128] = y;       // partial prefix (carry applied by K3)
    }
    Z[(b * NCV + c) * 128 + tid] = y;  // chunk aggregate
}

// ---------------------------------------------------------------------------
// K2: Kogge-Stone scan over the NCV chunk aggregates, IN-PLACE (P == Z).
// Block = (b, h, d8): 512 blocks, NCV threads (thread = chunk c).
// All global reads complete before the first global write; each block
// writes exactly the slice it read -> in-place safe.
// P[c] = alpha^(L*c) * v0 + S_inc[c-1]; P[0] = v0. Row stride 9 floats.
// ---------------------------------------------------------------------------
__global__ __launch_bounds__(NCV)
void k_scan(float4* __restrict__ ZP, const float* __restrict__ v0,
            const float* __restrict__ w) {
    __shared__ float lds[NCV][9];

    const int blk = blockIdx.x;        // b*64 + h*8 + d8
    const int b  = blk >> 6;
    const int h  = (blk >> 3) & 7;
    const int d8 = blk & 7;
    const int r4 = h * 16 + d8 * 2;
    const int tid = threadIdx.x;

    const float alpha = sigmoidf_(w[h]);
    const float aL = powf(alpha, (float)LCV);

    {
        float4 z0 = ZP[(b * NCV + tid) * 128 + r4];
        float4 z1 = ZP[(b * NCV + tid) * 128 + r4 + 1];
        lds[tid][0] = z0.x; lds[tid][1] = z0.y; lds[tid][2] = z0.z; lds[tid][3] = z0.w;
        lds[tid][4] = z1.x; lds[tid][5] = z1.y; lds[tid][6] = z1.z; lds[tid][7] = z1.w;
    }
    __syncthreads();

    const int c = tid;
    float s[8];
#pragma unroll
    for (int k = 0; k < 8; ++k) s[k] = lds[c][k];

    float m = aL;
    for (int off = 1; off < NCV; off <<= 1) {
        float tmp[8];
        const bool act = (c >= off);
        if (act) {
#pragma unroll
            for (int k = 0; k < 8; ++k) tmp[k] = lds[c - off][k];
        }
        __syncthreads();
        if (act) {
#pragma unroll
            for (int k = 0; k < 8; ++k) { s[k] += m * tmp[k]; lds[c][k] = s[k]; }
        }
        m *= m;
        __syncthreads();
    }

    const float pc = powf(alpha, (float)(LCV * c));
    const float4* v04 = (const float4*)v0;
#pragma unroll
    for (int k = 0; k < 2; ++k) {
        float4 vv = v04[r4 + k];
        float4 pr;
        if (c == 0) {
            pr = vv;
        } else {
            pr.x = pc * vv.x + lds[c - 1][k * 4 + 0];
            pr.y = pc * vv.y + lds[c - 1][k * 4 + 1];
            pr.z = pc * vv.z + lds[c - 1][k * 4 + 2];
            pr.w = pc * vv.w + lds[c - 1][k * 4 + 3];
        }
        ZP[(b * NCV + c) * 128 + r4 + k] = pr;   // in-place: P over Z
    }
}

// ---------------------------------------------------------------------------
// K3: elementwise fix-up: out[t] += alpha^(i+1) * P[c]   (t = c*L + i).
// Reads out (L3-hot from K1) + P (L3-hot from K2); never re-reads the
// 128 MB inputs. Final store is non-temporal (out is not re-read).
// ---------------------------------------------------------------------------
__global__ __launch_bounds__(128)
void k_final(const float* __restrict__ w, const f32x4* __restrict__ P,
             f32x4* __restrict__ out) {
    const int blk = blockIdx.x;
    const int b = blk >> 9;
    const int c = blk & (NCV - 1);
    const int tid = threadIdx.x;
    const int h = tid >> 4;

    const float alpha = sigmoidf_(w[h]);
    const f32x4 p = P[(b * NCV + c) * 128 + tid];
    const int base = (b * TT + c * LCV) * 128 + tid;

    float coef = alpha;
#pragma unroll
    for (int i = 0; i < LCV; ++i) {
        f32x4 o = out[base + i * 128];
        o.x += coef * p.x;
        o.y += coef * p.y;
        o.z += coef * p.z;
        o.w += coef * p.w;
        __builtin_nontemporal_store(o, &out[base + i * 128]);
        coef *= alpha;
    }
}

// ---------------------------------------------------------------------------
extern "C" void kernel_launch(void* const* d_in, const int* in_sizes, int n_in,
                              void* d_out, int out_size, void* d_ws, size_t ws_size,
                              hipStream_t stream) {
    const f32x4* vals = (const f32x4*)d_in[0];   // values  [B,T,H,D]
    const f32x4* aux  = (const f32x4*)d_in[1];   // aux     [B,T,H,D]
    const float* v0   = (const float*)d_in[2];   // v0      [H,D] = 512
    const float* w    = (const float*)d_in[3];   // weight  [H] = 8
    f32x4* out = (f32x4*)d_out;

    // Workspace: single Z/P buffer, B*NCV*128 f32x4 = 8.39 MB (in-place scan).
    f32x4* ZP = (f32x4*)d_ws;

    k_partial<<<GRID, 128, 0, stream>>>(vals, aux, w, out, ZP);
    k_scan<<<BB * HH * 8, NCV, 0, stream>>>((float4*)ZP, v0, w);
    k_final<<<GRID, 128, 0, stream>>>(w, ZP, out);
}